// Round 2
// baseline (201.398 us; speedup 1.0000x reference)
//
#include <hip/hip_runtime.h>
#include <stdint.h>

#define BB    2048
#define DIN   4096
#define DOUT  4096

// ---------------------------------------------------------------------------
// i8 MFMA bit-GEMM. x,m -> ±1 int8; dot± = 2*sums - 4096;
// out = sums > thr  <=>  dot± > 2*thr - 4096. Exact in i32. (R7: absmax 0)
// ws: x8 ±1 [BB][DIN] @0 (8 MB); m8T ±1 [DOUT][DIN] @8MB (16 MB).
//
// R9 post-mortem: counted-vmcnt 4-buffer BK=64 regressed (58us, MfmaUtil 22):
// doubling barrier count with 8 MFMA/phase cost more than the drain saved.
// Conflicts/FETCH unchanged -> bottleneck is LDS READ BW, not barriers:
// per CU R8 moved 6.1 MB LDS (~80-100Kcyc at 85B/cyc + 4-way quad tax) vs
// 116Kcyc wall. Fix the structural ratio: wave tile 64x64 reads 1/32 B/MAC;
// 128x64 reads 1/42.7 (0.75x). R10: block 256x128, 4 waves of 128x64
// (acc[4][2]), BK=128, dbuf, R8's single-syncthreads schedule, 96KB LDS,
// 256 blocks (1/CU). pack_all: ballot dtype-detect (4B load, no shfl chain)
// + 4 tiles/block (grid 6144->2048) to fix latency-bound 48us.
// ---------------------------------------------------------------------------

using v4i  = __attribute__((ext_vector_type(4)))  int;
using v16i = __attribute__((ext_vector_type(16))) int;

__device__ __forceinline__ void async_load16(const void* g, void* l) {
    __builtin_amdgcn_global_load_lds(
        (const __attribute__((address_space(1))) unsigned int*)g,
        (__attribute__((address_space(3))) unsigned int*)l,
        16, 0, 0);
}

// bytes {0,1} -> {+1, -1(0xFF)}; no cross-byte carries.
__device__ __forceinline__ unsigned int to_pm1(unsigned int c) {
    return c + ((c ^ 0x01010101u) * 255u);
}

// Fused packing.
// blocks [0,1024): two x rows {0,1}->±1 bytes (same layout).
// blocks [1024,2048): four 64x64 transpose tiles of masks -> m8T ±1 bytes.
__global__ void pack_all(const int* __restrict__ x,
                         const void* __restrict__ mraw,
                         char* __restrict__ x8,
                         char* __restrict__ m8T) {
    const int tid = threadIdx.x;
    if (blockIdx.x < 1024) {
        #pragma unroll
        for (int rr = 0; rr < 2; ++rr) {
            const int row = blockIdx.x * 2 + rr;
            const int4* src = (const int4*)(x + (size_t)row * DIN);
            unsigned int* dst = (unsigned int*)(x8 + (size_t)row * DIN);
            #pragma unroll
            for (int q = 0; q < 4; ++q) {
                int4 v = src[q * 256 + tid];           // coalesced 16B/lane
                unsigned int t = (unsigned int)(v.x & 1) |
                                 ((unsigned int)(v.y & 1) << 8) |
                                 ((unsigned int)(v.z & 1) << 16) |
                                 ((unsigned int)(v.w & 1) << 24);
                dst[q * 256 + tid] = to_pm1(t);        // coalesced 4B/lane
            }
        }
    } else {
        const int bw = blockIdx.x - 1024;          // 0..1023
        const int n0  = (bw >> 4) * 64;            // 64 n-tiles
        const int k0b = (bw & 15) * 256;           // 4 k-tiles per block

        // dtype detect (u8-bool vs int32), cheap + exact: int32 words are
        // {0,1}; u8-bool words exceed 1 unless 3 high bytes all zero
        // (P(miss) = 8^-64 per wave). One hot 4B load + ballot, no shfl.
        const unsigned char* mb = (const unsigned char*)mraw;
        const unsigned int pv = *(const unsigned int*)(mb + (tid & 63) * 4);
        const bool isU8 = __any(pv > 1u);

        // 4x4 byte micro-tile per thread: rows k0+k4..+3, cols n0+n4..+3
        const int n4 = (tid & 15) * 4;
        const int k4 = (tid >> 4) * 4;
        #pragma unroll
        for (int kt = 0; kt < 4; ++kt) {
            const int k0 = k0b + kt * 64;
            unsigned int a[4];
            if (isU8) {
                #pragma unroll
                for (int r = 0; r < 4; ++r)
                    a[r] = *(const unsigned int*)(mb + (size_t)(k0 + k4 + r) * DOUT + n0 + n4);
            } else {
                const int4* m32 = (const int4*)mraw;
                #pragma unroll
                for (int r = 0; r < 4; ++r) {
                    int4 v = m32[((size_t)(k0 + k4 + r) * DOUT + n0 + n4) >> 2];
                    a[r] = (unsigned int)(v.x & 1) |
                           ((unsigned int)(v.y & 1) << 8) |
                           ((unsigned int)(v.z & 1) << 16) |
                           ((unsigned int)(v.w & 1) << 24);
                }
            }
            // 4x4 byte transpose via v_perm (sel 0-3 = src1/lo, 4-7 = src0/hi)
            unsigned int x0 = __builtin_amdgcn_perm(a[1], a[0], 0x05010400u);
            unsigned int x1 = __builtin_amdgcn_perm(a[3], a[2], 0x05010400u);
            unsigned int x2 = __builtin_amdgcn_perm(a[1], a[0], 0x07030602u);
            unsigned int x3 = __builtin_amdgcn_perm(a[3], a[2], 0x07030602u);
            unsigned int c0 = __builtin_amdgcn_perm(x1, x0, 0x05040100u);
            unsigned int c1 = __builtin_amdgcn_perm(x1, x0, 0x07060302u);
            unsigned int c2 = __builtin_amdgcn_perm(x3, x2, 0x05040100u);
            unsigned int c3 = __builtin_amdgcn_perm(x3, x2, 0x07060302u);
            *(unsigned int*)(m8T + (size_t)(n0 + n4 + 0) * DIN + k0 + k4) = to_pm1(c0);
            *(unsigned int*)(m8T + (size_t)(n0 + n4 + 1) * DIN + k0 + k4) = to_pm1(c1);
            *(unsigned int*)(m8T + (size_t)(n0 + n4 + 2) * DIN + k0 + k4) = to_pm1(c2);
            *(unsigned int*)(m8T + (size_t)(n0 + n4 + 3) * DIN + k0 + k4) = to_pm1(c3);
        }
    }
}

// i8 MFMA GEMM: 256(m)x128(n) block tile, 4 waves as 2(m)x2(n) of 128x64
// wave tiles (4x2 of v_mfma_i32_32x32x32_i8 each). BK=128 chunks (32
// barriers), double-buffered LDS (96 KB, 1 block/CU), async global->LDS.
// LDS layout: [row][slot], slot = kgroup ^ (row&7), 8 kgroups x 16 B.
__global__ __launch_bounds__(256)
void bgemm(const char* __restrict__ x8,
           const char* __restrict__ m8T,
           const int* __restrict__ thr,
           int* __restrict__ out) {
    // XCD-aware swizzle: flat%8 = XCD; each XCD gets a compact 4m x 8n
    // patch (A 4MB + B 4MB per XCD).
    const int flat = blockIdx.x;                   // 0..255
    const int xcd  = flat & 7;
    const int idx  = flat >> 3;                    // 0..31
    const int bm   = (xcd & 1) * 4 + (idx & 3);    // 0..7
    const int bn   = (xcd >> 1) * 8 + (idx >> 2);  // 0..31
    const int b0   = bm * 256;                     // m
    const int o0   = bn * 128;                     // n

    const int tid  = threadIdx.x;
    const int lane = tid & 63;
    const int wv   = tid >> 6;
    const int wm   = (wv & 1) * 128;     // wave tile m origin
    const int wn   = (wv >> 1) * 64;     // wave tile n origin
    const int l31  = lane & 31;
    const int lh   = lane >> 5;
    const int rsw  = l31 & 7;            // row&7 term for frag reads

    __shared__ __align__(16) char lA[2][256 * 128];   // 64 KB
    __shared__ __align__(16) char lB[2][128 * 128];   // 32 KB

    // stage chunk c -> buf. Per instr: 8 rows x 128 B contiguous LDS (1KB,
    // wave-uniform base + lane*16 as global_load_lds requires).
    // lane: row = r0 + l/8, slot s = l&7, global kgroup g = s ^ (row&7).
    auto stage = [&](int c, int buf) {
        const int k0 = c * 128;
        const int r8 = lane >> 3;
        const int sl = lane & 7;
        #pragma unroll
        for (int h = 0; h < 8; ++h) {              // A: 64 rows/wave
            const int r0  = wv * 64 + h * 8;
            const int row = r0 + r8;
            const int g   = sl ^ (row & 7);
            async_load16(x8 + (size_t)(b0 + row) * DIN + k0 + g * 16,
                         &lA[buf][r0 * 128 + lane * 16]);
        }
        #pragma unroll
        for (int h = 0; h < 4; ++h) {              // B: 32 rows/wave
            const int r0  = wv * 32 + h * 8;
            const int row = r0 + r8;
            const int g   = sl ^ (row & 7);
            async_load16(m8T + (size_t)(o0 + row) * DIN + k0 + g * 16,
                         &lB[buf][r0 * 128 + lane * 16]);
        }
    };

    v16i acc[4][2];
    #pragma unroll
    for (int t = 0; t < 4; ++t)
        #pragma unroll
        for (int u = 0; u < 2; ++u)
            acc[t][u] = (v16i)(0);

    stage(0, 0);
    __syncthreads();

    for (int c = 0; c < 32; ++c) {
        const int buf = c & 1;
        if (c < 31) stage(c + 1, buf ^ 1);   // async, overlaps compute

        #pragma unroll
        for (int ks = 0; ks < 4; ++ks) {
            // slot of global kgroup (ks*2+lh) for this lane's rows
            // (rows wm/wn + t*32 + l31: row&7 == l31&7 == rsw)
            const int slot = ((ks * 2 + lh) ^ rsw) * 16;
            v4i aF[4], bF[2];
            #pragma unroll
            for (int t = 0; t < 4; ++t)
                aF[t] = *(const v4i*)&lA[buf][(wm + t * 32 + l31) * 128 + slot];
            #pragma unroll
            for (int u = 0; u < 2; ++u)
                bF[u] = *(const v4i*)&lB[buf][(wn + u * 32 + l31) * 128 + slot];
            #pragma unroll
            for (int t = 0; t < 4; ++t)
                #pragma unroll
                for (int u = 0; u < 2; ++u)
                    acc[t][u] = __builtin_amdgcn_mfma_i32_32x32x32_i8(
                        aF[t], bF[u], acc[t][u], 0, 0, 0);
        }
        __syncthreads();   // drains chunk+1 loads; releases buf
    }

    // epilogue: out = (dot± > 2*thr - 4096).
    // C/D layout (verified R7): col = lane&31; row = (reg&3)+8*(reg>>2)+4*(lane>>5).
    #pragma unroll
    for (int u = 0; u < 2; ++u) {
        const int o   = o0 + wn + u * 32 + l31;
        const int lim = 2 * thr[o] - DIN;
        #pragma unroll
        for (int t = 0; t < 4; ++t) {
            #pragma unroll
            for (int r = 0; r < 16; ++r) {
                const int rowl = (r & 3) + 8 * (r >> 2) + 4 * lh;
                const int b    = b0 + wm + t * 32 + rowl;
                out[(size_t)b * DOUT + o] = (acc[t][u][r] > lim) ? 1 : 0;
            }
        }
    }
}

extern "C" void kernel_launch(void* const* d_in, const int* in_sizes, int n_in,
                              void* d_out, int out_size, void* d_ws, size_t ws_size,
                              hipStream_t stream) {
    const int* x          = (const int*)d_in[0];
    const void* masks     = d_in[1];           // bool: u8 or int32 (detected inline)
    const int* thresholds = (const int*)d_in[2];
    int* out              = (int*)d_out;

    char* x8  = (char*)d_ws;                          // 8 MB
    char* m8T = (char*)d_ws + ((size_t)8 << 20);      // 16 MB

    pack_all<<<2048, 256, 0, stream>>>(x, masks, x8, m8T);
    bgemm<<<256, 256, 0, stream>>>(x8, m8T, thresholds, out);
}

// Round 3
// 174.592 us; speedup vs baseline: 1.1535x; 1.1535x over previous
//
#include <hip/hip_runtime.h>
#include <stdint.h>

#define BB    2048
#define DIN   4096
#define DOUT  4096

// ---------------------------------------------------------------------------
// i8 MFMA bit-GEMM. x,m -> ±1 int8; dot± = 2*sums - 4096;
// out = sums > thr  <=>  dot± > 2*thr - 4096. Exact in i32. (R7: absmax 0)
// ws: x8 ±1 [BB][DIN] @0 (8 MB); m8T ±1 [DOUT][DIN] @8MB (16 MB).
//
// R10 post-mortem: conflicts fell 4.19M->3.15M exactly as predicted (0.75x)
// but 96KB LDS -> 1 block/CU -> 1 wave/SIMD: nothing hides the barrier
// drain. R8's 48.4us came from 2 waves/SIMD. Model: per-CU wall = LDS read
// port (4096 reads x 16cyc = 65K) + writes 16K vs MFMA 37.5K/SIMD; the
// 4/read conflict is a b128 column-gather floor (32 lanes x 16B > 128B/cyc)
// -- not swizzle-fixable. Levers: reads/MFMA ratio + >=2 waves/SIMD.
// R11: block 256x128, 8 waves = 2m x 2n x 2k (split-K), wave tile 128x64
// (reads/MFMA 0.75), BK=128, TRIPLE-buffer LDS (144KB), depth-2 prefetch,
// ONE barrier/chunk with counted vmcnt(6) (0 only at last chunk). Split-K
// combine via LDS pool in epilogue. pack_all: reverted to R0 grid (proven
// 48us; R2's 4-tile variant cost ~6us), keep ballot dtype-detect.
// ---------------------------------------------------------------------------

using v4i  = __attribute__((ext_vector_type(4)))  int;
using v16i = __attribute__((ext_vector_type(16))) int;

__device__ __forceinline__ void async_load16(const void* g, void* l) {
    __builtin_amdgcn_global_load_lds(
        (const __attribute__((address_space(1))) unsigned int*)g,
        (__attribute__((address_space(3))) unsigned int*)l,
        16, 0, 0);
}

// bytes {0,1} -> {+1, -1(0xFF)}; no cross-byte carries.
__device__ __forceinline__ unsigned int to_pm1(unsigned int c) {
    return c + ((c ^ 0x01010101u) * 255u);
}

// Fused packing (R0 structure, proven 48us).
// blocks [0,BB): x int32 {0,1} row -> x8 ±1 bytes (same layout).
// blocks [BB, BB+4096): 64x64 transpose tile of masks -> m8T ±1 bytes.
__global__ void pack_all(const int* __restrict__ x,
                         const void* __restrict__ mraw,
                         char* __restrict__ x8,
                         char* __restrict__ m8T) {
    const int tid = threadIdx.x;
    if (blockIdx.x < BB) {
        const int row = blockIdx.x;
        const int4* src = (const int4*)(x + (size_t)row * DIN);
        unsigned int* dst = (unsigned int*)(x8 + (size_t)row * DIN);
        #pragma unroll
        for (int q = 0; q < 4; ++q) {
            int4 v = src[q * 256 + tid];           // coalesced 16B/lane
            unsigned int t = (unsigned int)(v.x & 1) |
                             ((unsigned int)(v.y & 1) << 8) |
                             ((unsigned int)(v.z & 1) << 16) |
                             ((unsigned int)(v.w & 1) << 24);
            dst[q * 256 + tid] = to_pm1(t);        // coalesced 4B/lane
        }
    } else {
        const int bw = blockIdx.x - BB;            // 0..4095
        const int k0 = (bw & 63) * 64;
        const int n0 = (bw >> 6) * 64;

        // dtype detect (u8-bool vs int32), cheap + exact: int32 words are
        // {0,1}; u8-bool words exceed 1 unless bytes 1-3 all zero
        // (P(miss) = 8^-64 per wave). One hot 4B load + ballot.
        const unsigned char* mb = (const unsigned char*)mraw;
        const unsigned int pv = *(const unsigned int*)(mb + (tid & 63) * 4);
        const bool isU8 = __any(pv > 1u);

        // 4x4 byte micro-tile per thread: rows k0+k4..+3, cols n0+n4..+3
        const int n4 = (tid & 15) * 4;
        const int k4 = (tid >> 4) * 4;
        unsigned int a[4];
        if (isU8) {
            #pragma unroll
            for (int r = 0; r < 4; ++r)
                a[r] = *(const unsigned int*)(mb + (size_t)(k0 + k4 + r) * DOUT + n0 + n4);
        } else {
            const int4* m32 = (const int4*)mraw;
            #pragma unroll
            for (int r = 0; r < 4; ++r) {
                int4 v = m32[((size_t)(k0 + k4 + r) * DOUT + n0 + n4) >> 2];
                a[r] = (unsigned int)(v.x & 1) |
                       ((unsigned int)(v.y & 1) << 8) |
                       ((unsigned int)(v.z & 1) << 16) |
                       ((unsigned int)(v.w & 1) << 24);
            }
        }
        // 4x4 byte transpose via v_perm (sel 0-3 = src1/lo, 4-7 = src0/hi)
        unsigned int x0 = __builtin_amdgcn_perm(a[1], a[0], 0x05010400u);
        unsigned int x1 = __builtin_amdgcn_perm(a[3], a[2], 0x05010400u);
        unsigned int x2 = __builtin_amdgcn_perm(a[1], a[0], 0x07030602u);
        unsigned int x3 = __builtin_amdgcn_perm(a[3], a[2], 0x07030602u);
        unsigned int c0 = __builtin_amdgcn_perm(x1, x0, 0x05040100u);
        unsigned int c1 = __builtin_amdgcn_perm(x1, x0, 0x07060302u);
        unsigned int c2 = __builtin_amdgcn_perm(x3, x2, 0x05040100u);
        unsigned int c3 = __builtin_amdgcn_perm(x3, x2, 0x07060302u);
        *(unsigned int*)(m8T + (size_t)(n0 + n4 + 0) * DIN + k0 + k4) = to_pm1(c0);
        *(unsigned int*)(m8T + (size_t)(n0 + n4 + 1) * DIN + k0 + k4) = to_pm1(c1);
        *(unsigned int*)(m8T + (size_t)(n0 + n4 + 2) * DIN + k0 + k4) = to_pm1(c2);
        *(unsigned int*)(m8T + (size_t)(n0 + n4 + 3) * DIN + k0 + k4) = to_pm1(c3);
    }
}

// i8 MFMA GEMM: 256(m)x128(n) block tile, 8 waves = 2m x 2n x 2k(split-K),
// wave tile 128x64 (acc[4][2], 4x2 of v_mfma_i32_32x32x32_i8 per ks).
// BK=128 chunks (32), triple-buffer LDS (144 KB), depth-2 prefetch, one
// raw s_barrier per chunk with counted vmcnt(6). Split-K combine via LDS.
// LDS layout: [row][slot], slot = kgroup ^ (row&7), 8 kgroups x 16 B.
__global__ __launch_bounds__(512)
void bgemm(const char* __restrict__ x8,
           const char* __restrict__ m8T,
           const int* __restrict__ thr,
           int* __restrict__ out) {
    // XCD-aware swizzle: flat%8 = XCD; each XCD a compact 4m x 8n patch.
    const int flat = blockIdx.x;                   // 0..255
    const int xcd  = flat & 7;
    const int idx  = flat >> 3;                    // 0..31
    const int bm   = (xcd & 1) * 4 + (idx & 3);    // 0..7
    const int bn   = (xcd >> 1) * 8 + (idx >> 2);  // 0..31
    const int b0   = bm * 256;                     // m
    const int o0   = bn * 128;                     // n

    const int tid  = threadIdx.x;
    const int lane = tid & 63;
    const int wv   = tid >> 6;           // 0..7
    const int im   = wv & 1;
    const int in_  = (wv >> 1) & 1;
    const int kh   = wv >> 2;            // split-K half: kgroups kh*4..kh*4+3
    const int wm   = im * 128;           // wave tile m origin
    const int wn   = in_ * 64;           // wave tile n origin
    const int l31  = lane & 31;
    const int lh   = lane >> 5;
    const int rsw  = l31 & 7;            // row&7 term for frag reads

    // 3 buffers x (A 32KB + B 16KB) = 144 KB; pool reused for split-K combine.
    __shared__ __align__(16) char lds[3 * 49152];

    // stage chunk c -> buf. Per instr: 8 rows x 128 B contiguous LDS (1KB).
    // lane: row = r0 + l/8, slot s = l&7, global kgroup g = s ^ (row&7).
    // 6 global_load_lds per thread per chunk (A:4, B:2).
    auto stage = [&](int c, int buf) {
        char* bufA = lds + buf * 49152;
        char* bufB = bufA + 32768;
        const int k0 = c * 128;
        const int r8 = lane >> 3;
        const int sl = lane & 7;
        #pragma unroll
        for (int h = 0; h < 4; ++h) {              // A: 32 rows/wave
            const int r0  = wv * 32 + h * 8;
            const int row = r0 + r8;
            const int g   = sl ^ (row & 7);
            async_load16(x8 + (size_t)(b0 + row) * DIN + k0 + g * 16,
                         bufA + r0 * 128 + lane * 16);
        }
        #pragma unroll
        for (int h = 0; h < 2; ++h) {              // B: 16 rows/wave
            const int r0  = wv * 16 + h * 8;
            const int row = r0 + r8;
            const int g   = sl ^ (row & 7);
            async_load16(m8T + (size_t)(o0 + row) * DIN + k0 + g * 16,
                         bufB + r0 * 128 + lane * 16);
        }
    };

    v16i acc[4][2];
    #pragma unroll
    for (int t = 0; t < 4; ++t)
        #pragma unroll
        for (int u = 0; u < 2; ++u)
            acc[t][u] = (v16i)(0);

    // prologue: depth-2 prefetch (12 loads/thread in flight).
    stage(0, 0);
    stage(1, 1);

    for (int c = 0; c < 32; ++c) {
        // drain exactly stage(c): leave stage(c+1) (6 loads) in flight.
        if (c < 31) asm volatile("s_waitcnt vmcnt(6)" ::: "memory");
        else        asm volatile("s_waitcnt vmcnt(0)" ::: "memory");
        __builtin_amdgcn_s_barrier();  // stage(c) visible everywhere; all
                                       // waves done computing c-1 -> buf free
        if (c < 30) stage(c + 2, (c + 2) % 3);

        const char* bufA = lds + (c % 3) * 49152;
        const char* bufB = bufA + 32768;
        #pragma unroll
        for (int ks = 0; ks < 2; ++ks) {
            // this wave's kgroups: kh*4 + ks*2 + lh
            const int slot = (((kh * 4 + ks * 2 + lh) ^ rsw)) * 16;
            v4i aF[4], bF[2];
            #pragma unroll
            for (int t = 0; t < 4; ++t)
                aF[t] = *(const v4i*)&bufA[(wm + t * 32 + l31) * 128 + slot];
            #pragma unroll
            for (int u = 0; u < 2; ++u)
                bF[u] = *(const v4i*)&bufB[(wn + u * 32 + l31) * 128 + slot];
            #pragma unroll
            for (int t = 0; t < 4; ++t)
                #pragma unroll
                for (int u = 0; u < 2; ++u)
                    acc[t][u] = __builtin_amdgcn_mfma_i32_32x32x32_i8(
                        aF[t], bF[u], acc[t][u], 0, 0, 0);
        }
    }
    __syncthreads();   // all compute done; lds pool free for combine

    // ---- split-K combine. Pair p = (im,in_): waves (p, kh=0) and (p, kh=1)
    // computed the same 128x64 tile over disjoint K halves. Each wave gives
    // one 64-row half via LDS and keeps the other: h=0 keeps t0,1 gives t2,3;
    // h=1 keeps t2,3 gives t0,1. Pool: per pair 8192 i32 (2 halves x 4096).
    int* pool = (int*)lds;                         // 128 KB used
    const int p = wv & 3;
    {
        const int give0 = kh ? 0 : 2;              // first given t
        const int bw_ = p * 8192 + (kh ? 0 : 1) * 4096;
        #pragma unroll
        for (int tt = 0; tt < 2; ++tt) {
            const int t = give0 + tt;
            #pragma unroll
            for (int u = 0; u < 2; ++u)
                #pragma unroll
                for (int r = 0; r < 16; ++r) {
                    const int rowl = (r & 3) + 8 * (r >> 2) + 4 * lh;
                    pool[bw_ + (tt * 32 + rowl) * 64 + u * 32 + l31] = acc[t][u][r];
                }
        }
    }
    __syncthreads();
    const int keep0 = kh ? 2 : 0;
    const int br_ = p * 8192 + kh * 4096;          // partner's gift = my kept rows
    #pragma unroll
    for (int tt = 0; tt < 2; ++tt) {
        const int t = keep0 + tt;
        #pragma unroll
        for (int u = 0; u < 2; ++u)
            #pragma unroll
            for (int r = 0; r < 16; ++r) {
                const int rowl = (r & 3) + 8 * (r >> 2) + 4 * lh;
                acc[t][u][r] += pool[br_ + (tt * 32 + rowl) * 64 + u * 32 + l31];
            }
    }

    // epilogue: out = (dot± > 2*thr - 4096).
    // C/D layout (verified R7): col = lane&31; row = (reg&3)+8*(reg>>2)+4*(lane>>5).
    #pragma unroll
    for (int u = 0; u < 2; ++u) {
        const int o   = o0 + wn + u * 32 + l31;
        const int lim = 2 * thr[o] - DIN;
        #pragma unroll
        for (int tt = 0; tt < 2; ++tt) {
            const int t = keep0 + tt;
            #pragma unroll
            for (int r = 0; r < 16; ++r) {
                const int rowl = (r & 3) + 8 * (r >> 2) + 4 * lh;
                const int b    = b0 + wm + kh * 64 + tt * 32 + rowl;
                out[(size_t)b * DOUT + o] = (acc[t][u][r] > lim) ? 1 : 0;
            }
        }
    }
}

extern "C" void kernel_launch(void* const* d_in, const int* in_sizes, int n_in,
                              void* d_out, int out_size, void* d_ws, size_t ws_size,
                              hipStream_t stream) {
    const int* x          = (const int*)d_in[0];
    const void* masks     = d_in[1];           // bool: u8 or int32 (detected inline)
    const int* thresholds = (const int*)d_in[2];
    int* out              = (int*)d_out;

    char* x8  = (char*)d_ws;                          // 8 MB
    char* m8T = (char*)d_ws + ((size_t)8 << 20);      // 16 MB

    pack_all<<<BB + 4096, 256, 0, stream>>>(x, masks, x8, m8T);
    bgemm<<<256, 512, 0, stream>>>(x8, m8T, thresholds, out);
}